// Round 9
// baseline (277.822 us; speedup 1.0000x reference)
//
#include <hip/hip_runtime.h>
#include <hip/hip_bf16.h>
#include <cstdint>
#include <cstddef>

// ---------------- types / helpers ----------------
typedef __bf16 bfx8 __attribute__((ext_vector_type(8)));   // 8 bf16 = 4 VGPR
typedef float  fx4  __attribute__((ext_vector_type(4)));   // 16x16 MFMA C/D
typedef float  fx16 __attribute__((ext_vector_type(16)));  // 32x32 MFMA C/D

#define MFMA_B16(a, b, c)  __builtin_amdgcn_mfma_f32_16x16x32_bf16((a), (b), (c), 0, 0, 0)
#define MFMA32(a, b, c)    __builtin_amdgcn_mfma_f32_32x32x16_bf16((a), (b), (c), 0, 0, 0)

#define GLD_LDS16(gsrc, ldst)                                                  \
  __builtin_amdgcn_global_load_lds(                                            \
      (const __attribute__((address_space(1))) void*)(gsrc),                   \
      (__attribute__((address_space(3))) void*)(ldst), 16, 0, 0)

static __device__ __forceinline__ unsigned short f2bf(float f) {
  union { float f; unsigned u; } v; v.f = f;
  unsigned r = v.u + 0x7fffu + ((v.u >> 16) & 1u);   // RTNE
  return (unsigned short)(r >> 16);
}

static __device__ __forceinline__ bfx8 ldb8(const void* p) {
  return *(const bfx8*)p;
}

static __device__ __forceinline__ unsigned pk2(float lo, float hi) {
  __hip_bfloat162 h2 = __float22bfloat162_rn(make_float2(lo, hi));
  union { __hip_bfloat162 h; unsigned u; } c; c.h = h2; return c.u;
}

// scale 8 packed bf16 by s (unpack -> mul -> repack)
static __device__ __forceinline__ bfx8 scale8(bfx8 x, float s) {
  union { bfx8 v; unsigned u[4]; } a; a.v = x;
  union { bfx8 v; unsigned u[4]; } r;
#pragma unroll
  for (int j = 0; j < 4; ++j) {
    union { unsigned u; float f; } lo, hi;
    lo.u = a.u[j] << 16;
    hi.u = a.u[j] & 0xffff0000u;
    r.u[j] = pk2(lo.f * s, hi.f * s);
  }
  return r.v;
}

// problem constants
#define BB 4
#define TT 2048
#define DD 1024
#define HH 16
#define HD 64

// ---------------- cast x: f32 -> bf16 ----------------
__global__ void k_cast(const float* __restrict__ in, unsigned short* __restrict__ out, int n) {
  int i = (blockIdx.x * blockDim.x + threadIdx.x) * 4;
  int stride = gridDim.x * blockDim.x * 4;
  for (; i < n; i += stride) {
    float4 v = *(const float4*)(in + i);
    ushort4 o;
    o.x = f2bf(v.x); o.y = f2bf(v.y); o.z = f2bf(v.z); o.w = f2bf(v.w);
    *(ushort4*)(out + i) = o;
  }
}

// ---------------- transpose + cast: in[R][C] f32 -> out[C][R] bf16 ----------------
__global__ void k_transpose(const float* __restrict__ in, unsigned short* __restrict__ out,
                            int R, int C) {
  __shared__ float tile[32][33];
  int c0 = blockIdx.x * 32, r0 = blockIdx.y * 32;
  int tx = threadIdx.x, ty = threadIdx.y;   // 32 x 8
#pragma unroll
  for (int dy = 0; dy < 32; dy += 8)
    tile[ty + dy][tx] = in[(size_t)(r0 + ty + dy) * C + (c0 + tx)];
  __syncthreads();
#pragma unroll
  for (int dy = 0; dy < 32; dy += 8)
    out[(size_t)(c0 + ty + dy) * R + (r0 + tx)] = f2bf(tile[tx][ty + dy]);
}

// ---------------- 8-wave phase-pipelined GEMM (T2+T3+T4+T5) ----------------
// C[M][N] = A[M][K] * Bt[N][K]^T. BM=256, BN=128, BK=64. 512 thr = 8 waves (4M x 2N).
// LDS: 2 dbuf x (A 256x64 + B 128x64) bf16 = 96 KB, st_16x32 XOR swizzle
// (byte ^= ((row&4)<<3), i.e. lin ^ ((lin>>9&1)<<5)). Staging: global_load_lds,
// linear dest + inverse-swizzled source (rule 21). Counted vmcnt(6), never 0
// in-loop (T4). Raw s_barrier (no vmcnt(0) drain). setprio around MFMA (T5).
//
// Schedule per K-tile kt: [stage(kt+1) -> other dbuf] ; vmcnt(6) ; barrier ;
//   ph0 {ds_read 12 ; MFMA 16 ; barrier} ; ph1 {ds_read 12 ; MFMA 16 ; barrier}.
// stage(kt+1) targets the dbuf freed by kt-1's closing barrier -> no WAR race.

// stage one K-tile: A 4 units of 64x64, B 2 units of 64x64 (8KB each; 512thr x 16B)
static __device__ __forceinline__ void stage_kt(
    const char* __restrict__ Ab, const char* __restrict__ Bb, int K, int kt,
    char* ldsA, char* ldsB, int tid, int w) {
  const int r8 = tid >> 3;           // row within 64-row unit
  const int cb = (tid & 7) * 16;     // byte col 0..112
#pragma unroll
  for (int u = 0; u < 4; ++u) {
    int row = u * 64 + r8;
    int scb = cb ^ ((row & 4) << 3);   // inverse swizzle on SOURCE (involution)
    GLD_LDS16(Ab + ((size_t)row * K + kt * 64) * 2 + scb, ldsA + u * 8192 + w * 1024);
  }
#pragma unroll
  for (int u = 0; u < 2; ++u) {
    int row = u * 64 + r8;
    int scb = cb ^ ((row & 4) << 3);
    GLD_LDS16(Bb + ((size_t)row * K + kt * 64) * 2 + scb, ldsB + u * 8192 + w * 1024);
  }
}

template <int EPI>
__global__ __launch_bounds__(512) void k_gemm8(
    const unsigned short* __restrict__ A,   // [M][K] bf16
    const unsigned short* __restrict__ Bt,  // [N][K] bf16
    float* __restrict__ outf,               // EPI==0
    int M, int N, int K,
    unsigned short* __restrict__ qb, unsigned short* __restrict__ kb,
    unsigned short* __restrict__ vtb) {
  __shared__ __align__(16) unsigned short Ls[2][24576];   // 96 KB

  const int tid  = threadIdx.x;
  const int lane = tid & 63;
  const int w    = tid >> 6;         // 0..7
  const int wr   = w >> 1;           // 0..3 : 64-row M slice
  const int wc   = w & 1;            // 0..1 : 64-col N slice
  const int n16  = lane & 15, g = lane >> 4;
  const int m0 = blockIdx.y * 256, n0 = blockIdx.x * 128;

  const char* Ab = (const char*)(A  + (size_t)m0 * K);
  const char* Bb = (const char*)(Bt + (size_t)n0 * K);
  const int NKT = K >> 6;

  fx4 acc[4][4] = {};   // [mf][nf]

  stage_kt(Ab, Bb, K, 0, (char*)Ls[0], (char*)Ls[0] + 32768, tid, w);

#pragma unroll 1
  for (int kt = 0; kt < NKT; ++kt) {
    if (kt + 1 < NKT) {
      const int d1 = (kt + 1) & 1;
      stage_kt(Ab, Bb, K, kt + 1, (char*)Ls[d1], (char*)Ls[d1] + 32768, tid, w);
      asm volatile("s_waitcnt vmcnt(6)" ::: "memory");   // kt resident; kt+1 in flight
    } else {
      asm volatile("s_waitcnt vmcnt(0)" ::: "memory");   // last tile: drain
    }
    asm volatile("s_barrier" ::: "memory");              // all waves' slices landed

    const char* La = (const char*)Ls[kt & 1];
    const char* Lb = La + 32768;

#pragma unroll
    for (int ph = 0; ph < 2; ++ph) {
      bfx8 af[2][2], bf[4][2];
#pragma unroll
      for (int mf2 = 0; mf2 < 2; ++mf2)
#pragma unroll
        for (int kk = 0; kk < 2; ++kk) {
          int row = wr * 64 + (ph * 2 + mf2) * 16 + n16;
          int cb  = kk * 64 + g * 16;
          af[mf2][kk] = ldb8(La + row * 128 + (cb ^ ((row & 4) << 3)));
        }
#pragma unroll
      for (int nf = 0; nf < 4; ++nf)
#pragma unroll
        for (int kk = 0; kk < 2; ++kk) {
          int row = wc * 64 + nf * 16 + n16;
          int cb  = kk * 64 + g * 16;
          bf[nf][kk] = ldb8(Lb + row * 128 + (cb ^ ((row & 4) << 3)));
        }
      __builtin_amdgcn_s_setprio(1);
#pragma unroll
      for (int kk = 0; kk < 2; ++kk)
#pragma unroll
        for (int mf2 = 0; mf2 < 2; ++mf2)
#pragma unroll
          for (int nf = 0; nf < 4; ++nf)
            acc[ph * 2 + mf2][nf] = MFMA_B16(af[mf2][kk], bf[nf][kk], acc[ph * 2 + mf2][nf]);
      __builtin_amdgcn_s_setprio(0);
      asm volatile("s_barrier" ::: "memory");            // phase close (keeps lockstep)
    }
  }

  // epilogue: C/D layout col = lane&15, row = (lane>>4)*4 + i
#pragma unroll
  for (int mf = 0; mf < 4; ++mf) {
#pragma unroll
    for (int nf = 0; nf < 4; ++nf) {
      int mrow = m0 + wr * 64 + mf * 16 + g * 4;
      int ncol = n0 + wc * 64 + nf * 16 + n16;
      if (EPI == 0) {
#pragma unroll
        for (int i = 0; i < 4; ++i)
          outf[(size_t)(mrow + i) * N + ncol] = acc[mf][nf][i];
      } else {
        int sec = ncol >> 10;         // 0=q 1=k 2=v
        int h   = (ncol >> 6) & 15;
        int d   = ncol & 63;
#pragma unroll
        for (int i = 0; i < 4; ++i) {
          int mm = mrow + i;
          int b  = mm >> 11;
          int t  = mm & 2047;
          unsigned short val = f2bf(acc[mf][nf][i]);
          if (sec == 0)
            qb[(((size_t)(b * HH + h) * TT + t) << 6) + d] = val;
          else if (sec == 1)
            kb[(((size_t)(b * HH + h) * TT + t) << 6) + d] = val;
          else
            vtb[((size_t)(b * HH + h) * HD + d) * TT + t] = val;
        }
      }
    }
  }
}

// ---------------- flash attention (R3 structure — best measured, 133.5 us) ----------------
// Swapped QK^T: S^T = mfma32(K, Q); lane owns q-col = lane&31, regs hold 16 kv slots.
// log2e/sqrt(D) folded into Q, so S is already in log2 domain.
struct KVfrag { bfx8 k0, k1, k2, k3, v0, v1, v2, v3; };

static __device__ __forceinline__ void load_kv(
    KVfrag& f, const unsigned short* __restrict__ kbase,
    const unsigned short* __restrict__ vbase, int kv0) {
  const unsigned short* kr = kbase + (size_t)kv0 * HD;
  f.k0 = ldb8(kr);       f.k1 = ldb8(kr + 16);
  f.k2 = ldb8(kr + 32);  f.k3 = ldb8(kr + 48);
  const unsigned short* vr = vbase + kv0;
  f.v0 = ldb8(vr);            f.v1 = ldb8(vr + 16);
  f.v2 = ldb8(vr + 32 * TT);  f.v3 = ldb8(vr + 32 * TT + 16);
}

template <bool MASK>
static __device__ __forceinline__ void attn_tile(
    const KVfrag& f, const bfx8* qf, int lim, int hi,
    float& m, float& l, fx16& o0, fx16& o1) {
  fx16 s = {};
  s = MFMA32(f.k0, qf[0], s);
  s = MFMA32(f.k1, qf[1], s);
  s = MFMA32(f.k2, qf[2], s);
  s = MFMA32(f.k3, qf[3], s);

  float t[16];
#pragma unroll
  for (int r = 0; r < 16; ++r) {
    int koff = (r & 3) + 8 * (r >> 2);
    t[r] = (!MASK || koff <= lim) ? s[r] : -__builtin_inff();
  }
  float x0 = fmaxf(t[0], t[1]),   x1 = fmaxf(t[2], t[3]);
  float x2 = fmaxf(t[4], t[5]),   x3 = fmaxf(t[6], t[7]);
  float x4 = fmaxf(t[8], t[9]),   x5 = fmaxf(t[10], t[11]);
  float x6 = fmaxf(t[12], t[13]), x7 = fmaxf(t[14], t[15]);
  float y0 = fmaxf(x0, x1), y1 = fmaxf(x2, x3), y2 = fmaxf(x4, x5), y3 = fmaxf(x6, x7);
  float mx = fmaxf(fmaxf(y0, y1), fmaxf(y2, y3));

  // defer-max (T13)
  bool need = mx > m + 8.0f;
  if (__ballot(need) != 0ull) {
    float mo   = fmaxf(mx, __shfl_xor(mx, 32));
    float mnew = fmaxf(m, mo);
    float alpha = __builtin_amdgcn_exp2f(m - mnew);
    m = mnew;
    l *= alpha;
#pragma unroll
    for (int r = 0; r < 16; ++r) { o0[r] *= alpha; o1[r] *= alpha; }
  }

  float p[16];
#pragma unroll
  for (int r = 0; r < 16; ++r) p[r] = __builtin_amdgcn_exp2f(t[r] - m);
  float s0 = (p[0] + p[1]) + (p[2] + p[3]);
  float s1 = (p[4] + p[5]) + (p[6] + p[7]);
  float s2 = (p[8] + p[9]) + (p[10] + p[11]);
  float s3 = (p[12] + p[13]) + (p[14] + p[15]);
  l += (s0 + s1) + (s2 + s3);

  // P (S^T C/D regs) -> PV B-fragment (slot (hi,j) <-> kv = 16c + 8*hi + j)
  union { unsigned u[4]; bfx8 v; } P0, P1;
#pragma unroll
  for (int c = 0; c < 2; ++c) {
    unsigned a0 = pk2(p[8*c+0], p[8*c+1]);
    unsigned a1 = pk2(p[8*c+2], p[8*c+3]);
    unsigned b0 = pk2(p[8*c+4], p[8*c+5]);
    unsigned b1 = pk2(p[8*c+6], p[8*c+7]);
    unsigned xa0 = __shfl_xor(a0, 32), xa1 = __shfl_xor(a1, 32);
    unsigned xb0 = __shfl_xor(b0, 32), xb1 = __shfl_xor(b1, 32);
    unsigned* U = c ? P1.u : P0.u;
    U[0] = hi ? xb0 : a0;
    U[1] = hi ? xb1 : a1;
    U[2] = hi ? b0 : xa0;
    U[3] = hi ? b1 : xa1;
  }
  o0 = MFMA32(f.v0, P0.v, o0);
  o0 = MFMA32(f.v1, P1.v, o0);
  o1 = MFMA32(f.v2, P0.v, o1);
  o1 = MFMA32(f.v3, P1.v, o1);
}

static __device__ __forceinline__ void run_qtile(
    int i, const unsigned short* __restrict__ qbb,
    const unsigned short* __restrict__ kbase,
    const unsigned short* __restrict__ vbase,
    unsigned short* __restrict__ ybase0,
    int l31, int hi) {
  const int q0 = i * 32;
  const float CL = 0.0450842346f;   // log2(e)/sqrt(D)
  const unsigned short* qp = qbb + (size_t)(q0 + l31) * HD + hi * 8;
  bfx8 qf[4];
#pragma unroll
  for (int dc = 0; dc < 4; ++dc) qf[dc] = scale8(ldb8(qp + dc * 16), CL);

  fx16 o0 = {}, o1 = {};
  float m = -__builtin_inff(), l = 0.f;
  const int nt = i + 1;
  const int lim = l31 - 4 * hi;

  KVfrag A, B;
  load_kv(A, kbase, vbase, 0);
  int t = 0;
  for (; t + 2 <= nt - 1; t += 2) {
    load_kv(B, kbase, vbase, (t + 1) * 32);
    attn_tile<false>(A, qf, 0, hi, m, l, o0, o1);
    load_kv(A, kbase, vbase, (t + 2) * 32);
    attn_tile<false>(B, qf, 0, hi, m, l, o0, o1);
  }
  if (t == nt - 2) {
    load_kv(B, kbase, vbase, (t + 1) * 32);
    attn_tile<false>(A, qf, 0, hi, m, l, o0, o1);
    attn_tile<true>(B, qf, lim, hi, m, l, o0, o1);
  } else {
    attn_tile<true>(A, qf, lim, hi, m, l, o0, o1);
  }

  l += __shfl_xor(l, 32);
  float inv = 1.0f / l;
  unsigned short* yp = ybase0 + (size_t)(q0 + l31) * DD + 4 * hi;
#pragma unroll
  for (int g = 0; g < 4; ++g) {
    ushort4 s4;
    s4.x = f2bf(o0[4*g+0] * inv); s4.y = f2bf(o0[4*g+1] * inv);
    s4.z = f2bf(o0[4*g+2] * inv); s4.w = f2bf(o0[4*g+3] * inv);
    *(ushort4*)(yp + 8 * g) = s4;
    s4.x = f2bf(o1[4*g+0] * inv); s4.y = f2bf(o1[4*g+1] * inv);
    s4.z = f2bf(o1[4*g+2] * inv); s4.w = f2bf(o1[4*g+3] * inv);
    *(ushort4*)(yp + 32 + 8 * g) = s4;
  }
}

// grid: B*H*8 blocks, 256 thr (4 waves). wave handles q-tile pair (i, 63-i).
__global__ __launch_bounds__(256) void k_attn(
    const unsigned short* __restrict__ qb,
    const unsigned short* __restrict__ kb,
    const unsigned short* __restrict__ vtb,
    unsigned short* __restrict__ yb) {
  const int tid  = threadIdx.x;
  const int lane = tid & 63;
  const int w    = tid >> 6;
  const int l31  = lane & 31;
  const int hi   = lane >> 5;

  int blk = blockIdx.x;
  int j  = blk & 7;
  int h  = (blk >> 3) & 15;
  int b  = blk >> 7;
  const int i = j * 4 + w;
  const size_t bh = (size_t)b * HH + h;

  const unsigned short* qbb   = qb  + bh * TT * HD;
  const unsigned short* kbase = kb  + bh * TT * HD + (size_t)l31 * HD + hi * 8;
  const unsigned short* vbase = vtb + (bh * HD + l31) * TT + hi * 8;
  unsigned short* ybase0      = yb  + (size_t)b * TT * DD + h * HD;

  run_qtile(i,      qbb, kbase, vbase, ybase0, l31, hi);
  run_qtile(63 - i, qbb, kbase, vbase, ybase0, l31, hi);
}

// ---------------- launch ----------------
extern "C" void kernel_launch(void* const* d_in, const int* in_sizes, int n_in,
                              void* d_out, int out_size, void* d_ws, size_t ws_size,
                              hipStream_t stream) {
  const float* x      = (const float*)d_in[0];
  const float* w_qkv  = (const float*)d_in[1];
  const float* w_proj = (const float*)d_in[2];
  float* out = (float*)d_out;

  char* ws = (char*)d_ws;
  unsigned short* xb     = (unsigned short*)(ws);
  unsigned short* wqkvT  = (unsigned short*)(ws + (size_t)(16u << 20));
  unsigned short* wprojT = (unsigned short*)(ws + (size_t)(22u << 20));
  unsigned short* qb     = (unsigned short*)(ws + (size_t)(24u << 20));
  unsigned short* kb     = (unsigned short*)(ws + (size_t)(40u << 20));
  unsigned short* vtb    = (unsigned short*)(ws + (size_t)(56u << 20));
  unsigned short* yb     = xb;   // x dead after GEMM1

  k_cast<<<4096, 256, 0, stream>>>(x, xb, BB * TT * DD);

  dim3 tb(32, 8);
  k_transpose<<<dim3(3 * DD / 32, DD / 32), tb, 0, stream>>>(w_qkv, wqkvT, DD, 3 * DD);
  k_transpose<<<dim3(DD / 32, DD / 32), tb, 0, stream>>>(w_proj, wprojT, DD, DD);

  // QKV projection: [8192,1024] x [1024,3072] -> 24 x 32 = 768 blocks (3 full rounds)
  k_gemm8<1><<<dim3(3 * DD / 128, BB * TT / 256), 512, 0, stream>>>(
      xb, wqkvT, nullptr, BB * TT, 3 * DD, DD, qb, kb, vtb);

  // causal flash attention (R3 balanced-pair grid)
  k_attn<<<BB * HH * 8, 256, 0, stream>>>(qb, kb, vtb, yb);

  // output projection: [8192,1024] x [1024,1024] -> 8 x 32 = 256 blocks (1 full round)
  k_gemm8<0><<<dim3(DD / 128, BB * TT / 256), 512, 0, stream>>>(
      yb, wprojT, out, BB * TT, DD, DD, nullptr, nullptr, nullptr);
}